// Round 1
// baseline (172.150 us; speedup 1.0000x reference)
//
#include <hip/hip_runtime.h>
#include <hip/hip_bf16.h>
#include <stdint.h>

typedef unsigned short u16;
typedef short short8 __attribute__((ext_vector_type(8)));
typedef float f32x4 __attribute__((ext_vector_type(4)));

#define SEQ 2048
#define EMB 1024
#define NH 16
#define HD 64
#define NB 2
#define ZP 2112  // SEQ + 64 pad, reversed z per (b,h)

__device__ inline u16 f2bf(float f) {
    uint32_t u = __builtin_bit_cast(uint32_t, f);
    uint32_t r = (u + 0x7FFFu + ((u >> 16) & 1u)) >> 16;
    return (u16)r;
}

// ---------------- cast fp32 -> bf16, vectorized ----------------
__global__ __launch_bounds__(256) void cast_kernel(const float* __restrict__ src,
                                                   u16* __restrict__ dst, int n4) {
    int i = blockIdx.x * 256 + threadIdx.x;
    if (i < n4) {
        float4 f = reinterpret_cast<const float4*>(src)[i];
        union { u16 u[4]; uint2 v; } o;
        o.u[0] = f2bf(f.x); o.u[1] = f2bf(f.y); o.u[2] = f2bf(f.z); o.u[3] = f2bf(f.w);
        reinterpret_cast<uint2*>(dst)[i] = o.v;
    }
}

// ---------------- logits: zl[b][h][s] = dot(x[b,s,:], W_A[h,:]) * 0.125 ----------------
__global__ __launch_bounds__(256) void logits_kernel(const float* __restrict__ x,
                                                     const float* __restrict__ W_A,
                                                     float* __restrict__ zl) {
    __shared__ float wa[NH * EMB]; // 64 KB
    int t = threadIdx.x;
    for (int i = t; i < NH * EMB / 4; i += 256)
        reinterpret_cast<float4*>(wa)[i] = reinterpret_cast<const float4*>(W_A)[i];
    __syncthreads();
    int w = t >> 6, l = t & 63;
    int row0 = blockIdx.x * 32 + w * 8;
    for (int rr = 0; rr < 8; rr++) {
        int gs = row0 + rr;           // 0..4095 = b*SEQ + s
        int b = gs >> 11, s = gs & 2047;
        const float* xr = x + (size_t)gs * EMB;
        float xv[16];
#pragma unroll
        for (int q = 0; q < 16; q++) xv[q] = xr[l + 64 * q];
#pragma unroll
        for (int h = 0; h < NH; h++) {
            float a = 0.f;
#pragma unroll
            for (int q = 0; q < 16; q++) a += xv[q] * wa[h * EMB + l + 64 * q];
#pragma unroll
            for (int off = 32; off; off >>= 1) a += __shfl_xor(a, off);
            if (l == h) zl[((size_t)b * NH + h) * SEQ + s] = a * 0.125f;
        }
    }
}

// ---------------- softmax over s per (b,h); store REVERSED bf16 with zero pad ----------------
__global__ __launch_bounds__(256) void softmax_kernel(const float* __restrict__ zl,
                                                      u16* __restrict__ zr) {
    int bh = blockIdx.x;
    const float* src = zl + (size_t)bh * SEQ;
    int t = threadIdx.x;
    int w = t >> 6, l = t & 63;
    __shared__ float red[4];
    __shared__ float bc;
    float v[8];
#pragma unroll
    for (int q = 0; q < 8; q++) v[q] = src[t + 256 * q];
    float m = v[0];
#pragma unroll
    for (int q = 1; q < 8; q++) m = fmaxf(m, v[q]);
#pragma unroll
    for (int off = 32; off; off >>= 1) m = fmaxf(m, __shfl_xor(m, off));
    if (l == 0) red[w] = m;
    __syncthreads();
    if (t == 0) bc = fmaxf(fmaxf(red[0], red[1]), fmaxf(red[2], red[3]));
    __syncthreads();
    m = bc;
    float s = 0.f;
#pragma unroll
    for (int q = 0; q < 8; q++) { v[q] = expf(v[q] - m); s += v[q]; }
#pragma unroll
    for (int off = 32; off; off >>= 1) s += __shfl_xor(s, off);
    if (l == 0) red[w] = s;
    __syncthreads();
    if (t == 0) bc = red[0] + red[1] + red[2] + red[3];
    __syncthreads();
    float inv = 1.0f / bc;
#pragma unroll
    for (int q = 0; q < 8; q++) {
        int sidx = t + 256 * q;
        zr[(size_t)bh * ZP + (SEQ - 1 - sidx)] = f2bf(v[q] * inv);
    }
    if (t < ZP - SEQ) zr[(size_t)bh * ZP + SEQ + t] = 0;
}

// ---------------- generic GEMM: C[M,N] = A[M,K] * B[N,K]^T (bf16 in, fp32 acc) ----------------
// OUTMODE 0: bf16 out; 1: fp32 out + bias
template <int OUTMODE>
__global__ __launch_bounds__(256) void gemm_bt(const u16* __restrict__ A,
                                               const u16* __restrict__ Bw,
                                               u16* __restrict__ Cb, float* __restrict__ Cf,
                                               const float* __restrict__ bias,
                                               int M, int N, int K) {
    __shared__ u16 As[128 * 32];
    __shared__ u16 Bs[128 * 32];
    const int t = threadIdx.x;
    const int m0 = blockIdx.y * 128, n0 = blockIdx.x * 128;
    const int w = t >> 6, l = t & 63;
    const int wr = w >> 1, wc = w & 1;
    const int lrow = l & 15, lk = l >> 4;
    f32x4 acc[4][4];
#pragma unroll
    for (int i = 0; i < 4; i++)
#pragma unroll
        for (int j = 0; j < 4; j++) acc[i][j] = (f32x4){0.f, 0.f, 0.f, 0.f};

    for (int k0 = 0; k0 < K; k0 += 32) {
#pragma unroll
        for (int i = 0; i < 2; i++) {
            int id = t + 256 * i;
            int row = id >> 2, c = id & 3;
            uint4 va = *reinterpret_cast<const uint4*>(A + (size_t)(m0 + row) * K + k0 + c * 8);
            *reinterpret_cast<uint4*>(&As[row * 32 + ((c ^ (row & 3)) * 8)]) = va;
            uint4 vb = *reinterpret_cast<const uint4*>(Bw + (size_t)(n0 + row) * K + k0 + c * 8);
            *reinterpret_cast<uint4*>(&Bs[row * 32 + ((c ^ (row & 3)) * 8)]) = vb;
        }
        __syncthreads();
        short8 af[4], bf[4];
#pragma unroll
        for (int mi = 0; mi < 4; mi++) {
            int row = wr * 64 + mi * 16 + lrow;
            af[mi] = *reinterpret_cast<const short8*>(&As[row * 32 + ((lk ^ (row & 3)) * 8)]);
        }
#pragma unroll
        for (int ni = 0; ni < 4; ni++) {
            int row = wc * 64 + ni * 16 + lrow;
            bf[ni] = *reinterpret_cast<const short8*>(&Bs[row * 32 + ((lk ^ (row & 3)) * 8)]);
        }
#pragma unroll
        for (int mi = 0; mi < 4; mi++)
#pragma unroll
            for (int ni = 0; ni < 4; ni++)
                acc[mi][ni] = __builtin_amdgcn_mfma_f32_16x16x32_bf16(af[mi], bf[ni], acc[mi][ni], 0, 0, 0);
        __syncthreads();
    }
#pragma unroll
    for (int mi = 0; mi < 4; mi++)
#pragma unroll
        for (int ni = 0; ni < 4; ni++)
#pragma unroll
            for (int r = 0; r < 4; r++) {
                int row = m0 + wr * 64 + mi * 16 + (l >> 4) * 4 + r;
                int col = n0 + wc * 64 + ni * 16 + lrow;
                if constexpr (OUTMODE == 0)
                    Cb[(size_t)row * N + col] = f2bf(acc[mi][ni][r]);
                else
                    Cf[(size_t)row * N + col] = acc[mi][ni][r] + bias[col];
            }
}

// ---------------- transpose v[b][s][e] -> vt[b][h][d][s] ----------------
__global__ __launch_bounds__(256) void transpose_v(const u16* __restrict__ v,
                                                   u16* __restrict__ vt) {
    int s0 = blockIdx.x * 64, e0 = blockIdx.y * 64, b = blockIdx.z;
    __shared__ u16 ts[64 * 72];
    int t = threadIdx.x;
#pragma unroll
    for (int i = 0; i < 2; i++) {
        int id = t + 256 * i;
        int sl = id >> 3, c = id & 7;
        union { u16 u[8]; uint4 v4; } buf;
        buf.v4 = *reinterpret_cast<const uint4*>(v + ((size_t)b * SEQ + s0 + sl) * EMB + e0 + c * 8);
#pragma unroll
        for (int q = 0; q < 8; q++) ts[(c * 8 + q) * 72 + sl] = buf.u[q];
    }
    __syncthreads();
    int h = e0 >> 6;
#pragma unroll
    for (int i = 0; i < 2; i++) {
        int id = t + 256 * i;
        int dl = id >> 3, c = id & 7;
        uint4 val = *reinterpret_cast<const uint4*>(&ts[dl * 72 + c * 8]);
        *reinterpret_cast<uint4*>(vt + ((size_t)(b * NH + h) * HD + dl) * SEQ + s0 + c * 8) = val;
    }
}

// ---------------- causal Toeplitz conv: out[i,d] = sum_{j<=i} z[i-j]*v[j,d] per (b,h) ----------
__global__ __launch_bounds__(256) void conv_kernel(const u16* __restrict__ zr,
                                                   const u16* __restrict__ vt,
                                                   u16* __restrict__ cv) {
    const int bh = blockIdx.y;
    const int b = bh >> 4, h = bh & 15;
    const int i0 = blockIdx.x * 128;
    __shared__ u16 As[128 * 32];
    __shared__ u16 Bs[64 * 32];
    __shared__ u16 zs[ZP];
    const int t = threadIdx.x;
    {
        const uint4* src = reinterpret_cast<const uint4*>(zr + (size_t)bh * ZP);
        uint4* dst = reinterpret_cast<uint4*>(zs);
        for (int id = t; id < ZP / 8; id += 256) dst[id] = src[id];
    }
    const int w = t >> 6, l = t & 63;
    const int wr = w >> 1, wc = w & 1;
    const int lrow = l & 15, lk = l >> 4;
    f32x4 acc[4][2];
#pragma unroll
    for (int i = 0; i < 4; i++)
#pragma unroll
        for (int j = 0; j < 2; j++) acc[i][j] = (f32x4){0.f, 0.f, 0.f, 0.f};
    const int nk = blockIdx.x * 4 + 4;
    __syncthreads();
    for (int kk = 0; kk < nk; kk++) {
        int k0 = kk * 32;
        {   // stage B tile (64 d-rows x 32 j-cols) from vt
            int row = t >> 2, c = t & 3;
            uint4 vb = *reinterpret_cast<const uint4*>(vt + ((size_t)bh * HD + row) * SEQ + k0 + c * 8);
            *reinterpret_cast<uint4*>(&Bs[row * 32 + ((c ^ (row & 3)) * 8)]) = vb;
        }
        {   // generate Toeplitz A tile from zs
            int ii = t >> 1, kq = (t & 1) * 16;
            int i = i0 + ii;
            union { u16 u[16]; uint4 v4[2]; } buf;
#pragma unroll
            for (int q = 0; q < 16; q++) {
                int idx = i - (k0 + kq + q);
                buf.u[q] = (idx >= 0) ? zs[SEQ - 1 - idx] : (u16)0;
            }
            int c0 = (t & 1) * 2;
            *reinterpret_cast<uint4*>(&As[ii * 32 + (((c0) ^ (ii & 3)) * 8)]) = buf.v4[0];
            *reinterpret_cast<uint4*>(&As[ii * 32 + (((c0 + 1) ^ (ii & 3)) * 8)]) = buf.v4[1];
        }
        __syncthreads();
        short8 af[4], bfr[2];
#pragma unroll
        for (int mi = 0; mi < 4; mi++) {
            int row = wr * 64 + mi * 16 + lrow;
            af[mi] = *reinterpret_cast<const short8*>(&As[row * 32 + ((lk ^ (row & 3)) * 8)]);
        }
#pragma unroll
        for (int ni = 0; ni < 2; ni++) {
            int row = wc * 32 + ni * 16 + lrow;
            bfr[ni] = *reinterpret_cast<const short8*>(&Bs[row * 32 + ((lk ^ (row & 3)) * 8)]);
        }
#pragma unroll
        for (int mi = 0; mi < 4; mi++)
#pragma unroll
            for (int ni = 0; ni < 2; ni++)
                acc[mi][ni] = __builtin_amdgcn_mfma_f32_16x16x32_bf16(af[mi], bfr[ni], acc[mi][ni], 0, 0, 0);
        __syncthreads();
    }
#pragma unroll
    for (int mi = 0; mi < 4; mi++)
#pragma unroll
        for (int ni = 0; ni < 2; ni++)
#pragma unroll
            for (int r = 0; r < 4; r++) {
                int row = i0 + wr * 64 + mi * 16 + (l >> 4) * 4 + r;
                int col = h * 64 + wc * 32 + ni * 16 + lrow;
                cv[((size_t)b * SEQ + row) * EMB + col] = f2bf(acc[mi][ni][r]);
            }
}

extern "C" void kernel_launch(void* const* d_in, const int* in_sizes, int n_in,
                              void* d_out, int out_size, void* d_ws, size_t ws_size,
                              hipStream_t stream) {
    const float* x   = (const float*)d_in[0];
    const float* W_A = (const float*)d_in[1];
    const float* W_V = (const float*)d_in[2];
    const float* W_O = (const float*)d_in[3];
    const float* b_O = (const float*)d_in[4];

    char* ws = (char*)d_ws;
    u16*   xb  = (u16*)(ws + 0);          // 8 MB   x bf16 [4096][1024]
    u16*   wvb = (u16*)(ws + 8388608);    // 2 MB   W_V bf16 [1024][1024]
    u16*   wob = (u16*)(ws + 10485760);   // 2 MB   W_O bf16
    float* zl  = (float*)(ws + 12582912); // 256 KB logits fp32 [B][H][S]
    u16*   zr  = (u16*)(ws + 12845056);   // 132 KB reversed softmax bf16 [B][H][ZP]
    u16*   vb  = (u16*)(ws + 12980224);   // 8 MB   v bf16 [4096][1024]
    u16*   vt  = (u16*)(ws + 21368832);   // 8 MB   v^T bf16 [B][H][D][S]
    u16*   cv  = (u16*)(ws + 29757440);   // 8 MB   conv out bf16 [4096][1024]

    cast_kernel<<<4096, 256, 0, stream>>>(x, xb, 1048576);
    cast_kernel<<<1024, 256, 0, stream>>>(W_V, wvb, 262144);
    cast_kernel<<<1024, 256, 0, stream>>>(W_O, wob, 262144);
    logits_kernel<<<128, 256, 0, stream>>>(x, W_A, zl);
    softmax_kernel<<<32, 256, 0, stream>>>(zl, zr);
    gemm_bt<0><<<dim3(8, 32), 256, 0, stream>>>(xb, wvb, vb, nullptr, nullptr, 4096, 1024, 1024);
    transpose_v<<<dim3(32, 16, 2), 256, 0, stream>>>(vb, vt);
    conv_kernel<<<dim3(16, 32), 256, 0, stream>>>(zr, vt, cv);
    gemm_bt<1><<<dim3(8, 32), 256, 0, stream>>>(cv, wob, nullptr, (float*)d_out, b_O, 4096, 1024, 1024);
}

// Round 2
// 118.039 us; speedup vs baseline: 1.4584x; 1.4584x over previous
//
#include <hip/hip_runtime.h>
#include <hip/hip_bf16.h>
#include <stdint.h>

typedef unsigned short u16;
typedef short short8 __attribute__((ext_vector_type(8)));
typedef float f32x4 __attribute__((ext_vector_type(4)));

#define SEQ 2048
#define EMB 1024
#define NH 16
#define HD 64
#define ZP 2112  // SEQ + 64 pad, reversed z per (b,h)

__device__ inline u16 f2bf(float f) {
    uint32_t u = __builtin_bit_cast(uint32_t, f);
    uint32_t r = (u + 0x7FFFu + ((u >> 16) & 1u)) >> 16;
    return (u16)r;
}

// ---------------- cast fp32 -> bf16, vectorized ----------------
__global__ __launch_bounds__(256) void cast_kernel(const float* __restrict__ src,
                                                   u16* __restrict__ dst, int n4) {
    int i = blockIdx.x * 256 + threadIdx.x;
    if (i < n4) {
        float4 f = reinterpret_cast<const float4*>(src)[i];
        union { u16 u[4]; uint2 v; } o;
        o.u[0] = f2bf(f.x); o.u[1] = f2bf(f.y); o.u[2] = f2bf(f.z); o.u[3] = f2bf(f.w);
        reinterpret_cast<uint2*>(dst)[i] = o.v;
    }
}

// ---------------- logits: zl[b][h][s] = dot(x[b,s,:], W_A[h,:]) * 0.125 ----------------
__global__ __launch_bounds__(256) void logits_kernel(const float* __restrict__ x,
                                                     const float* __restrict__ W_A,
                                                     float* __restrict__ zl) {
    __shared__ float wa[NH * EMB]; // 64 KB
    int t = threadIdx.x;
    for (int i = t; i < NH * EMB / 4; i += 256)
        reinterpret_cast<float4*>(wa)[i] = reinterpret_cast<const float4*>(W_A)[i];
    __syncthreads();
    int w = t >> 6, l = t & 63;
    int row0 = blockIdx.x * 16 + w * 4;
    for (int rr = 0; rr < 4; rr++) {
        int gs = row0 + rr;           // 0..4095 = b*SEQ + s
        int b = gs >> 11, s = gs & 2047;
        const float* xr = x + (size_t)gs * EMB;
        float xv[16];
#pragma unroll
        for (int q = 0; q < 16; q++) xv[q] = xr[l + 64 * q];
#pragma unroll
        for (int h = 0; h < NH; h++) {
            float a = 0.f;
#pragma unroll
            for (int q = 0; q < 16; q++) a += xv[q] * wa[h * EMB + l + 64 * q];
#pragma unroll
            for (int off = 32; off; off >>= 1) a += __shfl_xor(a, off);
            if (l == h) zl[((size_t)b * NH + h) * SEQ + s] = a * 0.125f;
        }
    }
}

// ---------------- softmax over s per (b,h); store REVERSED bf16 with zero pad ----------------
__global__ __launch_bounds__(256) void softmax_kernel(const float* __restrict__ zl,
                                                      u16* __restrict__ zr) {
    int bh = blockIdx.x;
    const float* src = zl + (size_t)bh * SEQ;
    int t = threadIdx.x;
    int w = t >> 6, l = t & 63;
    __shared__ float red[4];
    __shared__ float bc;
    float v[8];
#pragma unroll
    for (int q = 0; q < 8; q++) v[q] = src[t + 256 * q];
    float m = v[0];
#pragma unroll
    for (int q = 1; q < 8; q++) m = fmaxf(m, v[q]);
#pragma unroll
    for (int off = 32; off; off >>= 1) m = fmaxf(m, __shfl_xor(m, off));
    if (l == 0) red[w] = m;
    __syncthreads();
    if (t == 0) bc = fmaxf(fmaxf(red[0], red[1]), fmaxf(red[2], red[3]));
    __syncthreads();
    m = bc;
    float s = 0.f;
#pragma unroll
    for (int q = 0; q < 8; q++) { v[q] = expf(v[q] - m); s += v[q]; }
#pragma unroll
    for (int off = 32; off; off >>= 1) s += __shfl_xor(s, off);
    if (l == 0) red[w] = s;
    __syncthreads();
    if (t == 0) bc = red[0] + red[1] + red[2] + red[3];
    __syncthreads();
    float inv = 1.0f / bc;
#pragma unroll
    for (int q = 0; q < 8; q++) {
        int sidx = t + 256 * q;
        zr[(size_t)bh * ZP + (SEQ - 1 - sidx)] = f2bf(v[q] * inv);
    }
    if (t < ZP - SEQ) zr[(size_t)bh * ZP + SEQ + t] = 0;
}

// ---------------- generic GEMM: C[M,N] = A[M,K] * B[N,K]^T (bf16 in, fp32 acc) ----------------
// OUTMODE 0: bf16 out; 1: fp32 out + bias
template <int OUTMODE>
__global__ __launch_bounds__(256) void gemm_bt(const u16* __restrict__ A,
                                               const u16* __restrict__ Bw,
                                               u16* __restrict__ Cb, float* __restrict__ Cf,
                                               const float* __restrict__ bias,
                                               int M, int N, int K) {
    __shared__ u16 As[128 * 32];
    __shared__ u16 Bs[128 * 32];
    const int t = threadIdx.x;
    const int m0 = blockIdx.y * 128, n0 = blockIdx.x * 128;
    const int w = t >> 6, l = t & 63;
    const int wr = w >> 1, wc = w & 1;
    const int lrow = l & 15, lk = l >> 4;
    f32x4 acc[4][4];
#pragma unroll
    for (int i = 0; i < 4; i++)
#pragma unroll
        for (int j = 0; j < 4; j++) acc[i][j] = (f32x4){0.f, 0.f, 0.f, 0.f};

    for (int k0 = 0; k0 < K; k0 += 32) {
#pragma unroll
        for (int i = 0; i < 2; i++) {
            int id = t + 256 * i;
            int row = id >> 2, c = id & 3;
            uint4 va = *reinterpret_cast<const uint4*>(A + (size_t)(m0 + row) * K + k0 + c * 8);
            *reinterpret_cast<uint4*>(&As[row * 32 + ((c ^ (row & 3)) * 8)]) = va;
            uint4 vb = *reinterpret_cast<const uint4*>(Bw + (size_t)(n0 + row) * K + k0 + c * 8);
            *reinterpret_cast<uint4*>(&Bs[row * 32 + ((c ^ (row & 3)) * 8)]) = vb;
        }
        __syncthreads();
        short8 af[4], bf[4];
#pragma unroll
        for (int mi = 0; mi < 4; mi++) {
            int row = wr * 64 + mi * 16 + lrow;
            af[mi] = *reinterpret_cast<const short8*>(&As[row * 32 + ((lk ^ (row & 3)) * 8)]);
        }
#pragma unroll
        for (int ni = 0; ni < 4; ni++) {
            int row = wc * 64 + ni * 16 + lrow;
            bf[ni] = *reinterpret_cast<const short8*>(&Bs[row * 32 + ((lk ^ (row & 3)) * 8)]);
        }
#pragma unroll
        for (int mi = 0; mi < 4; mi++)
#pragma unroll
            for (int ni = 0; ni < 4; ni++)
                acc[mi][ni] = __builtin_amdgcn_mfma_f32_16x16x32_bf16(af[mi], bf[ni], acc[mi][ni], 0, 0, 0);
        __syncthreads();
    }
#pragma unroll
    for (int mi = 0; mi < 4; mi++)
#pragma unroll
        for (int ni = 0; ni < 4; ni++)
#pragma unroll
            for (int r = 0; r < 4; r++) {
                int row = m0 + wr * 64 + mi * 16 + (l >> 4) * 4 + r;
                int col = n0 + wc * 64 + ni * 16 + lrow;
                if constexpr (OUTMODE == 0)
                    Cb[(size_t)row * N + col] = f2bf(acc[mi][ni][r]);
                else
                    Cf[(size_t)row * N + col] = acc[mi][ni][r] + bias[col];
            }
}

// ---------------- causal Toeplitz conv, barrier-free ----------------
// out[b,i,h,:] = sum_{j<=i} z[b,h,i-j] * v[b,j,h,:]
// A[row][k] = zrev[2047-row+k] : rows are contiguous slices of zrev -> read
// fragments directly from dual-parity LDS copies (no A tile, no barriers).
// B fragments read directly from v^T[e][b*S+j] in global (L2-resident).
// 1024 independent wave-tasks: (bh, slice-pair (s,31-s), col-half), 66 steps each.
__global__ __launch_bounds__(256) void conv_kernel(const u16* __restrict__ zr,
                                                   const u16* __restrict__ vt2,
                                                   u16* __restrict__ cv) {
    const int bh = blockIdx.y;
    const int b = bh >> 4, h = bh & 15;
    __shared__ uint zsl[2176];  // [0..1087]=zrev dwords, [1088..]=zrev shifted by 1 elem
    const int t = threadIdx.x;
    {
        const uint* zp = reinterpret_cast<const uint*>(zr + (size_t)bh * ZP);
        for (int i = t; i < 1088; i += 256) {
            uint v0 = (i < 1056) ? zp[i] : 0u;
            uint v1 = (i < 1055) ? zp[i + 1] : 0u;
            zsl[i] = v0;
            zsl[1088 + i] = (v0 >> 16) | (v1 << 16);
        }
    }
    __syncthreads();

    const int w = t >> 6, l = t & 63;
    const int taskid = blockIdx.x * 4 + w;     // 0..31 within bh
    const int pp = taskid >> 1;                // slice-pair 0..15
    const int ch = taskid & 1;                 // col half
    const int lrow = l & 15;
    const int lk8 = (l >> 4) * 8;
    const int col0 = ch * 32;
    const int ebase = h * 64 + col0;           // e index base into vt2 [1024][4096]
    const size_t boff = (size_t)b * SEQ;

    int slices[2] = {pp, 31 - pp};
#pragma unroll 1
    for (int si = 0; si < 2; si++) {
        const int s = slices[si];
        const int row0 = s * 64;
        const int nk = 2 * s + 2;              // always even
        f32x4 acc[4][2];
#pragma unroll
        for (int i = 0; i < 4; i++)
#pragma unroll
            for (int j = 0; j < 2; j++) acc[i][j] = (f32x4){0.f, 0.f, 0.f, 0.f};

        union U { uint d[4]; short8 s8; };
        U b0[2], b1[2], a0[4], a1[4];

        // base for A reads: o = 2047 - (row0 + mi*16 + lrow) + k0 + lk8
        const int obase = 2047 - row0 - lrow + lk8;

        auto loadB = [&](int k0, U* bf) {
#pragma unroll
            for (int ni = 0; ni < 2; ni++) {
                const u16* p = vt2 + (((size_t)(ebase + ni * 16 + lrow)) << 12) + boff + k0 + lk8;
                bf[ni].d[0] = reinterpret_cast<const uint4*>(p)->x;
                *reinterpret_cast<uint4*>(bf[ni].d) = *reinterpret_cast<const uint4*>(p);
            }
        };
        auto loadA = [&](int k0, U* af) {
#pragma unroll
            for (int mi = 0; mi < 4; mi++) {
                int o = obase - mi * 16 + k0;
                uint adw = (uint)(o >> 1) + (uint)((o & 1) * 1088);
#pragma unroll
                for (int q = 0; q < 4; q++) af[mi].d[q] = zsl[adw + q];
            }
        };

        loadB(0, b0);
        for (int k0 = 0; k0 < nk * 32; k0 += 64) {
            loadB(k0 + 32, b1);
            loadA(k0, a0);
#pragma unroll
            for (int mi = 0; mi < 4; mi++)
#pragma unroll
                for (int ni = 0; ni < 2; ni++)
                    acc[mi][ni] = __builtin_amdgcn_mfma_f32_16x16x32_bf16(a0[mi].s8, b0[ni].s8, acc[mi][ni], 0, 0, 0);
            if (k0 + 64 < nk * 32) loadB(k0 + 64, b0);
            loadA(k0 + 32, a1);
#pragma unroll
            for (int mi = 0; mi < 4; mi++)
#pragma unroll
                for (int ni = 0; ni < 2; ni++)
                    acc[mi][ni] = __builtin_amdgcn_mfma_f32_16x16x32_bf16(a1[mi].s8, b1[ni].s8, acc[mi][ni], 0, 0, 0);
        }
#pragma unroll
        for (int mi = 0; mi < 4; mi++)
#pragma unroll
            for (int ni = 0; ni < 2; ni++)
#pragma unroll
                for (int r = 0; r < 4; r++) {
                    int row = row0 + mi * 16 + (l >> 4) * 4 + r;
                    int col = col0 + ni * 16 + lrow;
                    cv[((size_t)b * SEQ + row) * EMB + h * 64 + col] = f2bf(acc[mi][ni][r]);
                }
    }
}

extern "C" void kernel_launch(void* const* d_in, const int* in_sizes, int n_in,
                              void* d_out, int out_size, void* d_ws, size_t ws_size,
                              hipStream_t stream) {
    const float* x   = (const float*)d_in[0];
    const float* W_A = (const float*)d_in[1];
    const float* W_V = (const float*)d_in[2];
    const float* W_O = (const float*)d_in[3];
    const float* b_O = (const float*)d_in[4];

    char* ws = (char*)d_ws;
    u16*   xb  = (u16*)(ws + 0);          // 8 MB   x bf16 [4096][1024]
    u16*   wvb = (u16*)(ws + 8388608);    // 2 MB   W_V bf16 [1024][1024]
    u16*   wob = (u16*)(ws + 10485760);   // 2 MB   W_O bf16
    float* zl  = (float*)(ws + 12582912); // 256 KB logits fp32 [B][H][S]
    u16*   zr  = (u16*)(ws + 12845056);   // 132 KB reversed softmax bf16 [B][H][ZP]
    u16*   vt2 = (u16*)(ws + 12980224);   // 8 MB   v^T bf16 [1024][B*S]
    u16*   cv  = (u16*)(ws + 21368832);   // 8 MB   conv out bf16 [4096][1024]

    cast_kernel<<<4096, 256, 0, stream>>>(x, xb, 1048576);
    cast_kernel<<<1024, 256, 0, stream>>>(W_V, wvb, 262144);
    cast_kernel<<<1024, 256, 0, stream>>>(W_O, wob, 262144);
    logits_kernel<<<256, 256, 0, stream>>>(x, W_A, zl);
    softmax_kernel<<<32, 256, 0, stream>>>(zl, zr);
    // v^T[e][b*S+s] = sum_k W_V[e,k] * x[b,s,k]  (A=W_V, B=x -> C[e][bs])
    gemm_bt<0><<<dim3(32, 8), 256, 0, stream>>>(wvb, xb, vt2, nullptr, nullptr, 1024, 4096, 1024);
    conv_kernel<<<dim3(8, 32), 256, 0, stream>>>(zr, vt2, cv);
    gemm_bt<1><<<dim3(8, 32), 256, 0, stream>>>(cv, wob, nullptr, (float*)d_out, b_O, 4096, 1024, 1024);
}

// Round 3
// 113.453 us; speedup vs baseline: 1.5174x; 1.0404x over previous
//
#include <hip/hip_runtime.h>
#include <hip/hip_bf16.h>
#include <stdint.h>

typedef unsigned short u16;
typedef short short8 __attribute__((ext_vector_type(8)));
typedef float f32x4 __attribute__((ext_vector_type(4)));

#define SEQ 2048
#define EMB 1024
#define NH 16
#define HD 64
#define ZP 2112  // SEQ + 64 pad, reversed z per (b,h)

__device__ inline u16 f2bf(float f) {
    uint32_t u = __builtin_bit_cast(uint32_t, f);
    uint32_t r = (u + 0x7FFFu + ((u >> 16) & 1u)) >> 16;
    return (u16)r;
}

__device__ inline void gload16(const void* g, void* l) {
    __builtin_amdgcn_global_load_lds(
        (const __attribute__((address_space(1))) void*)g,
        (__attribute__((address_space(3))) void*)l, 16, 0, 0);
}

// ---------------- cast fp32 -> bf16, vectorized ----------------
__global__ __launch_bounds__(256) void cast_kernel(const float* __restrict__ src,
                                                   u16* __restrict__ dst, int n4) {
    int i = blockIdx.x * 256 + threadIdx.x;
    if (i < n4) {
        float4 f = reinterpret_cast<const float4*>(src)[i];
        union { u16 u[4]; uint2 v; } o;
        o.u[0] = f2bf(f.x); o.u[1] = f2bf(f.y); o.u[2] = f2bf(f.z); o.u[3] = f2bf(f.w);
        reinterpret_cast<uint2*>(dst)[i] = o.v;
    }
}

// ---------------- logits: zl[b][h][s] = dot(x[b,s,:], W_A[h,:]) * 0.125 ----------------
__global__ __launch_bounds__(256) void logits_kernel(const float* __restrict__ x,
                                                     const float* __restrict__ W_A,
                                                     float* __restrict__ zl) {
    __shared__ float wa[NH * EMB]; // 64 KB
    int t = threadIdx.x;
    for (int i = t; i < NH * EMB / 4; i += 256)
        reinterpret_cast<float4*>(wa)[i] = reinterpret_cast<const float4*>(W_A)[i];
    __syncthreads();
    int w = t >> 6, l = t & 63;
    int row0 = blockIdx.x * 16 + w * 4;
    for (int rr = 0; rr < 4; rr++) {
        int gs = row0 + rr;           // 0..4095 = b*SEQ + s
        int b = gs >> 11, s = gs & 2047;
        const float* xr = x + (size_t)gs * EMB;
        float xv[16];
#pragma unroll
        for (int q = 0; q < 16; q++) xv[q] = xr[l + 64 * q];
#pragma unroll
        for (int h = 0; h < NH; h++) {
            float a = 0.f;
#pragma unroll
            for (int q = 0; q < 16; q++) a += xv[q] * wa[h * EMB + l + 64 * q];
#pragma unroll
            for (int off = 32; off; off >>= 1) a += __shfl_xor(a, off);
            if (l == h) zl[((size_t)b * NH + h) * SEQ + s] = a * 0.125f;
        }
    }
}

// ---------------- softmax over s per (b,h); store REVERSED bf16 with zero pad ----------------
__global__ __launch_bounds__(256) void softmax_kernel(const float* __restrict__ zl,
                                                      u16* __restrict__ zr) {
    int bh = blockIdx.x;
    const float* src = zl + (size_t)bh * SEQ;
    int t = threadIdx.x;
    int w = t >> 6, l = t & 63;
    __shared__ float red[4];
    __shared__ float bc;
    float v[8];
#pragma unroll
    for (int q = 0; q < 8; q++) v[q] = src[t + 256 * q];
    float m = v[0];
#pragma unroll
    for (int q = 1; q < 8; q++) m = fmaxf(m, v[q]);
#pragma unroll
    for (int off = 32; off; off >>= 1) m = fmaxf(m, __shfl_xor(m, off));
    if (l == 0) red[w] = m;
    __syncthreads();
    if (t == 0) bc = fmaxf(fmaxf(red[0], red[1]), fmaxf(red[2], red[3]));
    __syncthreads();
    m = bc;
    float s = 0.f;
#pragma unroll
    for (int q = 0; q < 8; q++) { v[q] = expf(v[q] - m); s += v[q]; }
#pragma unroll
    for (int off = 32; off; off >>= 1) s += __shfl_xor(s, off);
    if (l == 0) red[w] = s;
    __syncthreads();
    if (t == 0) bc = red[0] + red[1] + red[2] + red[3];
    __syncthreads();
    float inv = 1.0f / bc;
#pragma unroll
    for (int q = 0; q < 8; q++) {
        int sidx = t + 256 * q;
        zr[(size_t)bh * ZP + (SEQ - 1 - sidx)] = f2bf(v[q] * inv);
    }
    if (t < ZP - SEQ) zr[(size_t)bh * ZP + SEQ + t] = 0;
}

// ---------------- generic GEMM: C[M,N] = A[M,K] * B[N,K]^T (bf16 in, fp32 acc) ----------------
// 512 threads = 8 waves (2x4), 128x128 tile, BK=32.
// Staging via global_load_lds (linear LDS dest) with PRE-SWIZZLED global source;
// ds_read uses the same XOR swizzle -> 2-way bank aliasing (free).
// OUTMODE 0: bf16 out; 1: fp32 out + bias
template <int OUTMODE>
__global__ __launch_bounds__(512) void gemm_bt(const u16* __restrict__ A,
                                               const u16* __restrict__ Bw,
                                               u16* __restrict__ Cb, float* __restrict__ Cf,
                                               const float* __restrict__ bias,
                                               int M, int N, int K) {
    __shared__ u16 As[128 * 32];
    __shared__ u16 Bs[128 * 32];
    const int t = threadIdx.x;
    const int m0 = blockIdx.y * 128, n0 = blockIdx.x * 128;
    const int w = t >> 6, l = t & 63;
    const int wr = w >> 2, wc = w & 3;       // wave tile: rows wr*64, cols wc*32
    const int lrow = l & 15, lk = l >> 4;

    // staging: wave w stages 16 rows (chunk w) of A and of B per K-step
    const int srow = w * 16 + (l >> 2);
    const int perm = (l & 3) ^ ((l >> 2) & 3) ^ ((l >> 4) & 3);
    const u16* gA = A + (size_t)(m0 + srow) * K + perm * 8;
    const u16* gB = Bw + (size_t)(n0 + srow) * K + perm * 8;
    u16* ldsA = &As[w * 512];
    u16* ldsB = &Bs[w * 512];

    f32x4 acc[4][2];
#pragma unroll
    for (int i = 0; i < 4; i++)
#pragma unroll
        for (int j = 0; j < 2; j++) acc[i][j] = (f32x4){0.f, 0.f, 0.f, 0.f};

    for (int k0 = 0; k0 < K; k0 += 32) {
        gload16(gA + k0, ldsA);
        gload16(gB + k0, ldsB);
        __syncthreads();
        short8 af[4], bf[2];
#pragma unroll
        for (int mi = 0; mi < 4; mi++) {
            int row = wr * 64 + mi * 16 + lrow;
            int g = lk ^ (row & 3) ^ ((row >> 2) & 3);
            af[mi] = *reinterpret_cast<const short8*>(&As[row * 32 + g * 8]);
        }
#pragma unroll
        for (int ni = 0; ni < 2; ni++) {
            int row = wc * 32 + ni * 16 + lrow;
            int g = lk ^ (row & 3) ^ ((row >> 2) & 3);
            bf[ni] = *reinterpret_cast<const short8*>(&Bs[row * 32 + g * 8]);
        }
#pragma unroll
        for (int mi = 0; mi < 4; mi++)
#pragma unroll
            for (int ni = 0; ni < 2; ni++)
                acc[mi][ni] = __builtin_amdgcn_mfma_f32_16x16x32_bf16(af[mi], bf[ni], acc[mi][ni], 0, 0, 0);
        __syncthreads();
    }
#pragma unroll
    for (int mi = 0; mi < 4; mi++)
#pragma unroll
        for (int ni = 0; ni < 2; ni++)
#pragma unroll
            for (int r = 0; r < 4; r++) {
                int row = m0 + wr * 64 + mi * 16 + (l >> 4) * 4 + r;
                int col = n0 + wc * 32 + ni * 16 + lrow;
                if constexpr (OUTMODE == 0)
                    Cb[(size_t)row * N + col] = f2bf(acc[mi][ni][r]);
                else
                    Cf[(size_t)row * N + col] = acc[mi][ni][r] + bias[col];
            }
}

// ---------------- causal Toeplitz conv, barrier-free ----------------
// out[b,i,h,:] = sum_{j<=i} z[b,h,i-j] * v[b,j,h,:]
// A[row][k] = zrev[2047-row+k] : rows are contiguous slices of zrev -> read
// fragments directly from dual-parity LDS copies (no A tile, no barriers).
// B fragments read directly from v^T[e][b*S+j] in global (L2-resident).
// 1024 independent wave-tasks: (bh, slice-pair (s,31-s), col-half), 66 steps each.
__global__ __launch_bounds__(256) void conv_kernel(const u16* __restrict__ zr,
                                                   const u16* __restrict__ vt2,
                                                   u16* __restrict__ cv) {
    const int bh = blockIdx.y;
    const int b = bh >> 4, h = bh & 15;
    __shared__ uint zsl[2176];  // [0..1087]=zrev dwords, [1088..]=zrev shifted by 1 elem
    const int t = threadIdx.x;
    {
        const uint* zp = reinterpret_cast<const uint*>(zr + (size_t)bh * ZP);
        for (int i = t; i < 1088; i += 256) {
            uint v0 = (i < 1056) ? zp[i] : 0u;
            uint v1 = (i < 1055) ? zp[i + 1] : 0u;
            zsl[i] = v0;
            zsl[1088 + i] = (v0 >> 16) | (v1 << 16);
        }
    }
    __syncthreads();

    const int w = t >> 6, l = t & 63;
    const int taskid = blockIdx.x * 4 + w;     // 0..31 within bh
    const int pp = taskid >> 1;                // slice-pair 0..15
    const int ch = taskid & 1;                 // col half
    const int lrow = l & 15;
    const int lk8 = (l >> 4) * 8;
    const int col0 = ch * 32;
    const int ebase = h * 64 + col0;           // e index base into vt2 [1024][4096]
    const size_t boff = (size_t)b * SEQ;

    int slices[2] = {pp, 31 - pp};
#pragma unroll 1
    for (int si = 0; si < 2; si++) {
        const int s = slices[si];
        const int row0 = s * 64;
        const int nk = 2 * s + 2;              // always even
        f32x4 acc[4][2];
#pragma unroll
        for (int i = 0; i < 4; i++)
#pragma unroll
            for (int j = 0; j < 2; j++) acc[i][j] = (f32x4){0.f, 0.f, 0.f, 0.f};

        union U { uint d[4]; short8 s8; };
        U b0[2], b1[2], a0[4], a1[4];

        // base for A reads: o = 2047 - (row0 + mi*16 + lrow) + k0 + lk8
        const int obase = 2047 - row0 - lrow + lk8;

        auto loadB = [&](int k0, U* bf) {
#pragma unroll
            for (int ni = 0; ni < 2; ni++) {
                const u16* p = vt2 + (((size_t)(ebase + ni * 16 + lrow)) << 12) + boff + k0 + lk8;
                *reinterpret_cast<uint4*>(bf[ni].d) = *reinterpret_cast<const uint4*>(p);
            }
        };
        auto loadA = [&](int k0, U* af) {
#pragma unroll
            for (int mi = 0; mi < 4; mi++) {
                int o = obase - mi * 16 + k0;
                uint adw = (uint)(o >> 1) + (uint)((o & 1) * 1088);
#pragma unroll
                for (int q = 0; q < 4; q++) af[mi].d[q] = zsl[adw + q];
            }
        };

        loadB(0, b0);
        for (int k0 = 0; k0 < nk * 32; k0 += 64) {
            loadB(k0 + 32, b1);
            loadA(k0, a0);
#pragma unroll
            for (int mi = 0; mi < 4; mi++)
#pragma unroll
                for (int ni = 0; ni < 2; ni++)
                    acc[mi][ni] = __builtin_amdgcn_mfma_f32_16x16x32_bf16(a0[mi].s8, b0[ni].s8, acc[mi][ni], 0, 0, 0);
            if (k0 + 64 < nk * 32) loadB(k0 + 64, b0);
            loadA(k0 + 32, a1);
#pragma unroll
            for (int mi = 0; mi < 4; mi++)
#pragma unroll
                for (int ni = 0; ni < 2; ni++)
                    acc[mi][ni] = __builtin_amdgcn_mfma_f32_16x16x32_bf16(a1[mi].s8, b1[ni].s8, acc[mi][ni], 0, 0, 0);
        }
#pragma unroll
        for (int mi = 0; mi < 4; mi++)
#pragma unroll
            for (int ni = 0; ni < 2; ni++)
#pragma unroll
                for (int r = 0; r < 4; r++) {
                    int row = row0 + mi * 16 + (l >> 4) * 4 + r;
                    int col = col0 + ni * 16 + lrow;
                    cv[((size_t)b * SEQ + row) * EMB + h * 64 + col] = f2bf(acc[mi][ni][r]);
                }
    }
}

extern "C" void kernel_launch(void* const* d_in, const int* in_sizes, int n_in,
                              void* d_out, int out_size, void* d_ws, size_t ws_size,
                              hipStream_t stream) {
    const float* x   = (const float*)d_in[0];
    const float* W_A = (const float*)d_in[1];
    const float* W_V = (const float*)d_in[2];
    const float* W_O = (const float*)d_in[3];
    const float* b_O = (const float*)d_in[4];

    char* ws = (char*)d_ws;
    u16*   xb  = (u16*)(ws + 0);          // 8 MB   x bf16 [4096][1024]
    u16*   wvb = (u16*)(ws + 8388608);    // 2 MB   W_V bf16 [1024][1024]
    u16*   wob = (u16*)(ws + 10485760);   // 2 MB   W_O bf16
    float* zl  = (float*)(ws + 12582912); // 256 KB logits fp32 [B][H][S]
    u16*   zr  = (u16*)(ws + 12845056);   // 132 KB reversed softmax bf16 [B][H][ZP]
    u16*   vt2 = (u16*)(ws + 12980224);   // 8 MB   v^T bf16 [1024][B*S]
    u16*   cv  = (u16*)(ws + 21368832);   // 8 MB   conv out bf16 [4096][1024]

    cast_kernel<<<4096, 256, 0, stream>>>(x, xb, 1048576);
    cast_kernel<<<1024, 256, 0, stream>>>(W_V, wvb, 262144);
    cast_kernel<<<1024, 256, 0, stream>>>(W_O, wob, 262144);
    logits_kernel<<<256, 256, 0, stream>>>(x, W_A, zl);
    softmax_kernel<<<32, 256, 0, stream>>>(zl, zr);
    // v^T[e][b*S+s] = sum_k W_V[e,k] * x[b,s,k]  (A=W_V, B=x -> C[e][bs])
    gemm_bt<0><<<dim3(32, 8), 512, 0, stream>>>(wvb, xb, vt2, nullptr, nullptr, 1024, 4096, 1024);
    conv_kernel<<<dim3(8, 32), 256, 0, stream>>>(zr, vt2, cv);
    gemm_bt<1><<<dim3(8, 32), 512, 0, stream>>>(cv, wob, nullptr, (float*)d_out, b_O, 4096, 1024, 1024);
}

// Round 4
// 103.526 us; speedup vs baseline: 1.6629x; 1.0959x over previous
//
#include <hip/hip_runtime.h>
#include <hip/hip_bf16.h>
#include <stdint.h>

typedef unsigned short u16;
typedef short short8 __attribute__((ext_vector_type(8)));
typedef float f32x4 __attribute__((ext_vector_type(4)));

#define SEQ 2048
#define EMB 1024
#define NH 16
#define HD 64
#define ZP 2112  // SEQ + 64 pad, reversed z per (b,h)

__device__ inline u16 f2bf(float f) {
    uint32_t u = __builtin_bit_cast(uint32_t, f);
    uint32_t r = (u + 0x7FFFu + ((u >> 16) & 1u)) >> 16;
    return (u16)r;
}

__device__ inline void gload16(const void* g, void* l) {
    __builtin_amdgcn_global_load_lds(
        (const __attribute__((address_space(1))) void*)g,
        (__attribute__((address_space(3))) void*)l, 16, 0, 0);
}

// ---------------- cast fp32 -> bf16, vectorized ----------------
__global__ __launch_bounds__(256) void cast_kernel(const float* __restrict__ src,
                                                   u16* __restrict__ dst, int n4) {
    int i = blockIdx.x * 256 + threadIdx.x;
    if (i < n4) {
        float4 f = reinterpret_cast<const float4*>(src)[i];
        union { u16 u[4]; uint2 v; } o;
        o.u[0] = f2bf(f.x); o.u[1] = f2bf(f.y); o.u[2] = f2bf(f.z); o.u[3] = f2bf(f.w);
        reinterpret_cast<uint2*>(dst)[i] = o.v;
    }
}

// cast both weight matrices in one launch (saves a dispatch)
__global__ __launch_bounds__(256) void cast2_kernel(const float* __restrict__ s0,
                                                    u16* __restrict__ d0,
                                                    const float* __restrict__ s1,
                                                    u16* __restrict__ d1, int n4each) {
    int i = blockIdx.x * 256 + threadIdx.x;
    const float* src = (i < n4each) ? s0 : s1;
    u16* dst = (i < n4each) ? d0 : d1;
    int j = (i < n4each) ? i : i - n4each;
    float4 f = reinterpret_cast<const float4*>(src)[j];
    union { u16 u[4]; uint2 v; } o;
    o.u[0] = f2bf(f.x); o.u[1] = f2bf(f.y); o.u[2] = f2bf(f.z); o.u[3] = f2bf(f.w);
    reinterpret_cast<uint2*>(dst)[j] = o.v;
}

// ---------------- logits: zl[b][h][s] = dot(x[b,s,:], W_A[h,:]) * 0.125 ----------------
__global__ __launch_bounds__(256) void logits_kernel(const float* __restrict__ x,
                                                     const float* __restrict__ W_A,
                                                     float* __restrict__ zl) {
    __shared__ float wa[NH * EMB]; // 64 KB
    int t = threadIdx.x;
    for (int i = t; i < NH * EMB / 4; i += 256)
        reinterpret_cast<float4*>(wa)[i] = reinterpret_cast<const float4*>(W_A)[i];
    __syncthreads();
    int w = t >> 6, l = t & 63;
    int row0 = blockIdx.x * 16 + w * 4;
    for (int rr = 0; rr < 4; rr++) {
        int gs = row0 + rr;           // 0..4095 = b*SEQ + s
        int b = gs >> 11, s = gs & 2047;
        const float* xr = x + (size_t)gs * EMB;
        float xv[16];
#pragma unroll
        for (int q = 0; q < 16; q++) xv[q] = xr[l + 64 * q];
#pragma unroll
        for (int h = 0; h < NH; h++) {
            float a = 0.f;
#pragma unroll
            for (int q = 0; q < 16; q++) a += xv[q] * wa[h * EMB + l + 64 * q];
#pragma unroll
            for (int off = 32; off; off >>= 1) a += __shfl_xor(a, off);
            if (l == h) zl[((size_t)b * NH + h) * SEQ + s] = a * 0.125f;
        }
    }
}

// ---------------- softmax over s per (b,h); store REVERSED bf16 with zero pad ----------------
__global__ __launch_bounds__(256) void softmax_kernel(const float* __restrict__ zl,
                                                      u16* __restrict__ zr) {
    int bh = blockIdx.x;
    const float* src = zl + (size_t)bh * SEQ;
    int t = threadIdx.x;
    int w = t >> 6, l = t & 63;
    __shared__ float red[4];
    __shared__ float bc;
    float v[8];
#pragma unroll
    for (int q = 0; q < 8; q++) v[q] = src[t + 256 * q];
    float m = v[0];
#pragma unroll
    for (int q = 1; q < 8; q++) m = fmaxf(m, v[q]);
#pragma unroll
    for (int off = 32; off; off >>= 1) m = fmaxf(m, __shfl_xor(m, off));
    if (l == 0) red[w] = m;
    __syncthreads();
    if (t == 0) bc = fmaxf(fmaxf(red[0], red[1]), fmaxf(red[2], red[3]));
    __syncthreads();
    m = bc;
    float s = 0.f;
#pragma unroll
    for (int q = 0; q < 8; q++) { v[q] = expf(v[q] - m); s += v[q]; }
#pragma unroll
    for (int off = 32; off; off >>= 1) s += __shfl_xor(s, off);
    if (l == 0) red[w] = s;
    __syncthreads();
    if (t == 0) bc = red[0] + red[1] + red[2] + red[3];
    __syncthreads();
    float inv = 1.0f / bc;
#pragma unroll
    for (int q = 0; q < 8; q++) {
        int sidx = t + 256 * q;
        zr[(size_t)bh * ZP + (SEQ - 1 - sidx)] = f2bf(v[q] * inv);
    }
    if (t < ZP - SEQ) zr[(size_t)bh * ZP + SEQ + t] = 0;
}

// ---------------- GEMM: C[M,N] = A[M,K] * B[N,K]^T, 2-phase pipelined ----------------
// 512 threads = 8 waves (2x4), 128x128 tile, BK=64, double-buffered LDS.
// Next tile's global_load_lds issued BEFORE current tile's ds_read+MFMA; one
// vmcnt-drain barrier per K-tile (T3 minimum recipe). Linear LDS dest +
// pre-swizzled global src + XOR'd ds_read (c' = cb ^ (row&7)) -> 2-way = free.
// OUTMODE 0: bf16 out; 1: fp32 out + bias
template <int OUTMODE>
__global__ __launch_bounds__(512) void gemm_bt(const u16* __restrict__ A,
                                               const u16* __restrict__ Bw,
                                               u16* __restrict__ Cb, float* __restrict__ Cf,
                                               const float* __restrict__ bias,
                                               int M, int N, int K) {
    __shared__ u16 As[2][128 * 64];
    __shared__ u16 Bs[2][128 * 64];
    const int t = threadIdx.x;
    const int m0 = blockIdx.y * 128, n0 = blockIdx.x * 128;
    const int w = t >> 6, l = t & 63;
    const int wr = w >> 2, wc = w & 3;       // wave tile: rows wr*64, cols wc*32
    const int lrow = l & 15, lk = l >> 4;
    const int r7 = lrow & 7;

    // staging: wave w stages rows w*16..w*16+15 of A and B (2 gload16 each)
    const int srow = w * 16 + (l >> 3);
    const int scb = ((l & 7) ^ (l >> 3)) * 8;   // pre-swizzled source col (bf16)
    const u16* gA0 = A + (size_t)(m0 + srow) * K + scb;
    const u16* gA1 = gA0 + (size_t)8 * K;
    const u16* gB0 = Bw + (size_t)(n0 + srow) * K + scb;
    const u16* gB1 = gB0 + (size_t)8 * K;
    const int ldsbase = w * 16 * 64;            // u16 units

    f32x4 acc[4][2];
#pragma unroll
    for (int i = 0; i < 4; i++)
#pragma unroll
        for (int j = 0; j < 2; j++) acc[i][j] = (f32x4){0.f, 0.f, 0.f, 0.f};

    const int NT = K >> 6;
    // prologue
    gload16(gA0, &As[0][ldsbase]);
    gload16(gA1, &As[0][ldsbase + 512]);
    gload16(gB0, &Bs[0][ldsbase]);
    gload16(gB1, &Bs[0][ldsbase + 512]);
    __syncthreads();

    for (int kt = 0; kt < NT; kt++) {
        const int cur = kt & 1;
        if (kt + 1 < NT) {
            const int k0 = (kt + 1) * 64;
            gload16(gA0 + k0, &As[cur ^ 1][ldsbase]);
            gload16(gA1 + k0, &As[cur ^ 1][ldsbase + 512]);
            gload16(gB0 + k0, &Bs[cur ^ 1][ldsbase]);
            gload16(gB1 + k0, &Bs[cur ^ 1][ldsbase + 512]);
        }
#pragma unroll
        for (int kk = 0; kk < 2; kk++) {
            const int cs = ((kk * 4 + lk) ^ r7) * 8;
            short8 af[4], bf2[2];
#pragma unroll
            for (int mi = 0; mi < 4; mi++)
                af[mi] = *reinterpret_cast<const short8*>(
                    &As[cur][(wr * 64 + mi * 16 + lrow) * 64 + cs]);
#pragma unroll
            for (int ni = 0; ni < 2; ni++)
                bf2[ni] = *reinterpret_cast<const short8*>(
                    &Bs[cur][(wc * 32 + ni * 16 + lrow) * 64 + cs]);
#pragma unroll
            for (int mi = 0; mi < 4; mi++)
#pragma unroll
                for (int ni = 0; ni < 2; ni++)
                    acc[mi][ni] = __builtin_amdgcn_mfma_f32_16x16x32_bf16(af[mi], bf2[ni], acc[mi][ni], 0, 0, 0);
        }
        __syncthreads();
    }
#pragma unroll
    for (int mi = 0; mi < 4; mi++)
#pragma unroll
        for (int ni = 0; ni < 2; ni++)
#pragma unroll
            for (int r = 0; r < 4; r++) {
                int row = m0 + wr * 64 + mi * 16 + (l >> 4) * 4 + r;
                int col = n0 + wc * 32 + ni * 16 + lrow;
                if constexpr (OUTMODE == 0)
                    Cb[(size_t)row * N + col] = f2bf(acc[mi][ni][r]);
                else
                    Cf[(size_t)row * N + col] = acc[mi][ni][r] + bias[col];
            }
}

// ---------------- causal Toeplitz conv, barrier-free ----------------
// out[b,i,h,:] = sum_{j<=i} z[b,h,i-j] * v[b,j,h,:]
// A[row][k] = zrev[2047-row+k] : rows are contiguous slices of zrev -> read
// fragments directly from dual-parity LDS copies (no A tile, no barriers).
// B fragments read directly from v^T[e][b*S+j] in global (L2-resident).
// 1024 independent wave-tasks: (bh, slice-pair (s,31-s), col-half), 66 steps each.
__global__ __launch_bounds__(256) void conv_kernel(const u16* __restrict__ zr,
                                                   const u16* __restrict__ vt2,
                                                   u16* __restrict__ cv) {
    const int bh = blockIdx.y;
    const int b = bh >> 4, h = bh & 15;
    __shared__ uint zsl[2176];  // [0..1087]=zrev dwords, [1088..]=zrev shifted by 1 elem
    const int t = threadIdx.x;
    {
        const uint* zp = reinterpret_cast<const uint*>(zr + (size_t)bh * ZP);
        for (int i = t; i < 1088; i += 256) {
            uint v0 = (i < 1056) ? zp[i] : 0u;
            uint v1 = (i < 1055) ? zp[i + 1] : 0u;
            zsl[i] = v0;
            zsl[1088 + i] = (v0 >> 16) | (v1 << 16);
        }
    }
    __syncthreads();

    const int w = t >> 6, l = t & 63;
    const int taskid = blockIdx.x * 4 + w;     // 0..31 within bh
    const int pp = taskid >> 1;                // slice-pair 0..15
    const int ch = taskid & 1;                 // col half
    const int lrow = l & 15;
    const int lk8 = (l >> 4) * 8;
    const int col0 = ch * 32;
    const int ebase = h * 64 + col0;           // e index base into vt2 [1024][4096]
    const size_t boff = (size_t)b * SEQ;

    int slices[2] = {pp, 31 - pp};
#pragma unroll 1
    for (int si = 0; si < 2; si++) {
        const int s = slices[si];
        const int row0 = s * 64;
        const int nk = 2 * s + 2;              // always even
        f32x4 acc[4][2];
#pragma unroll
        for (int i = 0; i < 4; i++)
#pragma unroll
            for (int j = 0; j < 2; j++) acc[i][j] = (f32x4){0.f, 0.f, 0.f, 0.f};

        union U { uint d[4]; short8 s8; };
        U b0[2], b1[2], a0[4], a1[4];

        // base for A reads: o = 2047 - (row0 + mi*16 + lrow) + k0 + lk8
        const int obase = 2047 - row0 - lrow + lk8;

        auto loadB = [&](int k0, U* bf) {
#pragma unroll
            for (int ni = 0; ni < 2; ni++) {
                const u16* p = vt2 + (((size_t)(ebase + ni * 16 + lrow)) << 12) + boff + k0 + lk8;
                *reinterpret_cast<uint4*>(bf[ni].d) = *reinterpret_cast<const uint4*>(p);
            }
        };
        auto loadA = [&](int k0, U* af) {
#pragma unroll
            for (int mi = 0; mi < 4; mi++) {
                int o = obase - mi * 16 + k0;
                uint adw = (uint)(o >> 1) + (uint)((o & 1) * 1088);
#pragma unroll
                for (int q = 0; q < 4; q++) af[mi].d[q] = zsl[adw + q];
            }
        };

        loadB(0, b0);
        for (int k0 = 0; k0 < nk * 32; k0 += 64) {
            loadB(k0 + 32, b1);
            loadA(k0, a0);
#pragma unroll
            for (int mi = 0; mi < 4; mi++)
#pragma unroll
                for (int ni = 0; ni < 2; ni++)
                    acc[mi][ni] = __builtin_amdgcn_mfma_f32_16x16x32_bf16(a0[mi].s8, b0[ni].s8, acc[mi][ni], 0, 0, 0);
            if (k0 + 64 < nk * 32) loadB(k0 + 64, b0);
            loadA(k0 + 32, a1);
#pragma unroll
            for (int mi = 0; mi < 4; mi++)
#pragma unroll
                for (int ni = 0; ni < 2; ni++)
                    acc[mi][ni] = __builtin_amdgcn_mfma_f32_16x16x32_bf16(a1[mi].s8, b1[ni].s8, acc[mi][ni], 0, 0, 0);
        }
#pragma unroll
        for (int mi = 0; mi < 4; mi++)
#pragma unroll
            for (int ni = 0; ni < 2; ni++)
#pragma unroll
                for (int r = 0; r < 4; r++) {
                    int row = row0 + mi * 16 + (l >> 4) * 4 + r;
                    int col = col0 + ni * 16 + lrow;
                    cv[((size_t)b * SEQ + row) * EMB + h * 64 + col] = f2bf(acc[mi][ni][r]);
                }
    }
}

extern "C" void kernel_launch(void* const* d_in, const int* in_sizes, int n_in,
                              void* d_out, int out_size, void* d_ws, size_t ws_size,
                              hipStream_t stream) {
    const float* x   = (const float*)d_in[0];
    const float* W_A = (const float*)d_in[1];
    const float* W_V = (const float*)d_in[2];
    const float* W_O = (const float*)d_in[3];
    const float* b_O = (const float*)d_in[4];

    char* ws = (char*)d_ws;
    u16*   xb  = (u16*)(ws + 0);          // 8 MB   x bf16 [4096][1024]
    u16*   wvb = (u16*)(ws + 8388608);    // 2 MB   W_V bf16 [1024][1024]
    u16*   wob = (u16*)(ws + 10485760);   // 2 MB   W_O bf16
    float* zl  = (float*)(ws + 12582912); // 256 KB logits fp32 [B][H][S]
    u16*   zr  = (u16*)(ws + 12845056);   // 132 KB reversed softmax bf16 [B][H][ZP]
    u16*   vt2 = (u16*)(ws + 12980224);   // 8 MB   v^T bf16 [1024][B*S]
    u16*   cv  = (u16*)(ws + 21368832);   // 8 MB   conv out bf16 [4096][1024]

    cast_kernel<<<4096, 256, 0, stream>>>(x, xb, 1048576);
    cast2_kernel<<<2048, 256, 0, stream>>>(W_V, wvb, W_O, wob, 262144);
    logits_kernel<<<256, 256, 0, stream>>>(x, W_A, zl);
    softmax_kernel<<<32, 256, 0, stream>>>(zl, zr);
    // v^T[e][b*S+s] = sum_k W_V[e,k] * x[b,s,k]  (A=W_V, B=x -> C[e][bs])
    gemm_bt<0><<<dim3(32, 8), 512, 0, stream>>>(wvb, xb, vt2, nullptr, nullptr, 1024, 4096, 1024);
    conv_kernel<<<dim3(8, 32), 256, 0, stream>>>(zr, vt2, cv);
    gemm_bt<1><<<dim3(8, 32), 512, 0, stream>>>(cv, wob, nullptr, (float*)d_out, b_O, 4096, 1024, 1024);
}

// Round 5
// 103.103 us; speedup vs baseline: 1.6697x; 1.0041x over previous
//
#include <hip/hip_runtime.h>
#include <hip/hip_bf16.h>
#include <stdint.h>

typedef unsigned short u16;
typedef short short8 __attribute__((ext_vector_type(8)));
typedef float f32x4 __attribute__((ext_vector_type(4)));

#define SEQ 2048
#define EMB 1024
#define NH 16
#define HD 64
#define ZP 2112  // SEQ + 64 pad, reversed z per (b,h)

__device__ inline u16 f2bf(float f) {
    uint32_t u = __builtin_bit_cast(uint32_t, f);
    uint32_t r = (u + 0x7FFFu + ((u >> 16) & 1u)) >> 16;
    return (u16)r;
}

__device__ inline void gload16(const void* g, void* l) {
    __builtin_amdgcn_global_load_lds(
        (const __attribute__((address_space(1))) void*)g,
        (__attribute__((address_space(3))) void*)l, 16, 0, 0);
}

// ---------------- all casts fused: x, W_V, W_O fp32 -> bf16 ----------------
__global__ __launch_bounds__(256) void cast_all(const float* __restrict__ x,
                                                const float* __restrict__ W_V,
                                                const float* __restrict__ W_O,
                                                u16* __restrict__ xb,
                                                u16* __restrict__ wvb,
                                                u16* __restrict__ wob) {
    int bid = blockIdx.x, t = threadIdx.x;
    const float* src;
    u16* dst;
    int j;
    if (bid < 4096) { j = bid * 256 + t; src = x; dst = xb; }
    else {
        j = (bid - 4096) * 256 + t;
        if (j < 262144) { src = W_V; dst = wvb; }
        else { j -= 262144; src = W_O; dst = wob; }
    }
    float4 f = reinterpret_cast<const float4*>(src)[j];
    union { u16 u[4]; uint2 v; } o;
    o.u[0] = f2bf(f.x); o.u[1] = f2bf(f.y); o.u[2] = f2bf(f.z); o.u[3] = f2bf(f.w);
    reinterpret_cast<uint2*>(dst)[j] = o.v;
}

// ---------------- logits: zl[b][h][s] = dot(x[b,s,:], W_A[h,:]) * 0.125 ----------------
__global__ __launch_bounds__(256) void logits_kernel(const float* __restrict__ x,
                                                     const float* __restrict__ W_A,
                                                     float* __restrict__ zl) {
    __shared__ float wa[NH * EMB]; // 64 KB
    int t = threadIdx.x;
    for (int i = t; i < NH * EMB / 4; i += 256)
        reinterpret_cast<float4*>(wa)[i] = reinterpret_cast<const float4*>(W_A)[i];
    __syncthreads();
    int w = t >> 6, l = t & 63;
    int row0 = blockIdx.x * 16 + w * 4;
    for (int rr = 0; rr < 4; rr++) {
        int gs = row0 + rr;           // 0..4095 = b*SEQ + s
        int b = gs >> 11, s = gs & 2047;
        const float* xr = x + (size_t)gs * EMB;
        float xv[16];
#pragma unroll
        for (int q = 0; q < 16; q++) xv[q] = xr[l + 64 * q];
#pragma unroll
        for (int h = 0; h < NH; h++) {
            float a = 0.f;
#pragma unroll
            for (int q = 0; q < 16; q++) a += xv[q] * wa[h * EMB + l + 64 * q];
#pragma unroll
            for (int off = 32; off; off >>= 1) a += __shfl_xor(a, off);
            if (l == h) zl[((size_t)b * NH + h) * SEQ + s] = a * 0.125f;
        }
    }
}

// ---------------- softmax body (per bh), 256 threads ----------------
__device__ void softmax_body(const float* __restrict__ zl, u16* __restrict__ zr, int bh) {
    const float* src = zl + (size_t)bh * SEQ;
    int t = threadIdx.x;
    int w = t >> 6, l = t & 63;
    __shared__ float red[4];
    __shared__ float bc;
    float v[8];
#pragma unroll
    for (int q = 0; q < 8; q++) v[q] = src[t + 256 * q];
    float m = v[0];
#pragma unroll
    for (int q = 1; q < 8; q++) m = fmaxf(m, v[q]);
#pragma unroll
    for (int off = 32; off; off >>= 1) m = fmaxf(m, __shfl_xor(m, off));
    if (l == 0) red[w] = m;
    __syncthreads();
    if (t == 0) bc = fmaxf(fmaxf(red[0], red[1]), fmaxf(red[2], red[3]));
    __syncthreads();
    m = bc;
    float s = 0.f;
#pragma unroll
    for (int q = 0; q < 8; q++) { v[q] = expf(v[q] - m); s += v[q]; }
#pragma unroll
    for (int off = 32; off; off >>= 1) s += __shfl_xor(s, off);
    if (l == 0) red[w] = s;
    __syncthreads();
    if (t == 0) bc = red[0] + red[1] + red[2] + red[3];
    __syncthreads();
    float inv = 1.0f / bc;
#pragma unroll
    for (int q = 0; q < 8; q++) {
        int sidx = t + 256 * q;
        zr[(size_t)bh * ZP + (SEQ - 1 - sidx)] = f2bf(v[q] * inv);
    }
    if (t < ZP - SEQ) zr[(size_t)bh * ZP + SEQ + t] = 0;
}

// ---------------- GEMM: C[M,N] = A[M,K] * B[N,K]^T ----------------
// 128x64 tile, 256 threads (4 waves, 2x2), BK=64, double-buffered, 2-phase.
// 512 blocks -> 2 blocks/CU so barrier drains overlap across blocks.
// XCD swizzle: MAP 0 groups same-x (share B panel), MAP 1 groups same-y (share A).
// SM: blocks >= 512 run softmax instead (fused independent work).
// OUTMODE 0: bf16 out; 1: fp32 out + bias
template <int OUTMODE, int MAP, bool SM>
__global__ __launch_bounds__(256) void gemm64(const u16* __restrict__ A,
                                              const u16* __restrict__ Bw,
                                              u16* __restrict__ Cb, float* __restrict__ Cf,
                                              const float* __restrict__ bias,
                                              int M, int N, int K,
                                              const float* __restrict__ zl,
                                              u16* __restrict__ zr) {
    if constexpr (SM) {
        if (blockIdx.x >= 512) { softmax_body(zl, zr, blockIdx.x - 512); return; }
    }
    __shared__ u16 As[2][128 * 64];
    __shared__ u16 Bs[2][64 * 64];
    const int t = threadIdx.x;
    const int i = blockIdx.x;
    int xg, yg;
    if constexpr (MAP == 0) { xg = (i & 7) * 8 + ((i >> 3) & 7); yg = i >> 6; }
    else                    { yg = (i & 7) * 4 + ((i >> 3) & 3); xg = i >> 5; }
    const int m0 = yg * 128, n0 = xg * 64;
    const int w = t >> 6, l = t & 63;
    const int wr = w >> 1, wc = w & 1;       // wave tile 64 rows x 32 cols
    const int lrow = l & 15, lk = l >> 4;
    const int r7 = lrow & 7;

    // staging addresses: linear LDS dest, pre-swizzled global source chunk
    const int srow = t >> 3;                  // 0..31
    const int scb = ((t & 7) ^ ((t >> 3) & 7)) * 8;
    const u16* gA = A + (size_t)(m0 + srow) * K + scb;   // + 32*i rows per call
    const u16* gB = Bw + (size_t)(n0 + srow) * K + scb;
    const int ldst = w * 512;                 // u16 offset of wave's chunk per call

    f32x4 acc[4][2];
#pragma unroll
    for (int a = 0; a < 4; a++)
#pragma unroll
        for (int b = 0; b < 2; b++) acc[a][b] = (f32x4){0.f, 0.f, 0.f, 0.f};

    const int NT = K >> 6;
    const size_t rk32 = (size_t)32 * K;
    // prologue: stage tile 0
#pragma unroll
    for (int c = 0; c < 4; c++) gload16(gA + c * rk32, &As[0][ldst + 2048 * c]);
#pragma unroll
    for (int c = 0; c < 2; c++) gload16(gB + c * rk32, &Bs[0][ldst + 2048 * c]);
    __syncthreads();

    for (int kt = 0; kt < NT; kt++) {
        const int cur = kt & 1;
        if (kt + 1 < NT) {
            const int k0 = (kt + 1) * 64;
#pragma unroll
            for (int c = 0; c < 4; c++) gload16(gA + k0 + c * rk32, &As[cur ^ 1][ldst + 2048 * c]);
#pragma unroll
            for (int c = 0; c < 2; c++) gload16(gB + k0 + c * rk32, &Bs[cur ^ 1][ldst + 2048 * c]);
        }
#pragma unroll
        for (int kk = 0; kk < 2; kk++) {
            const int cs = ((kk * 4 + lk) ^ r7) * 8;
            short8 af[4], bf2[2];
#pragma unroll
            for (int mi = 0; mi < 4; mi++)
                af[mi] = *reinterpret_cast<const short8*>(
                    &As[cur][(wr * 64 + mi * 16 + lrow) * 64 + cs]);
#pragma unroll
            for (int ni = 0; ni < 2; ni++)
                bf2[ni] = *reinterpret_cast<const short8*>(
                    &Bs[cur][(wc * 32 + ni * 16 + lrow) * 64 + cs]);
#pragma unroll
            for (int mi = 0; mi < 4; mi++)
#pragma unroll
                for (int ni = 0; ni < 2; ni++)
                    acc[mi][ni] = __builtin_amdgcn_mfma_f32_16x16x32_bf16(af[mi], bf2[ni], acc[mi][ni], 0, 0, 0);
        }
        __syncthreads();
    }
#pragma unroll
    for (int mi = 0; mi < 4; mi++)
#pragma unroll
        for (int ni = 0; ni < 2; ni++)
#pragma unroll
            for (int r = 0; r < 4; r++) {
                int row = m0 + wr * 64 + mi * 16 + lk * 4 + r;
                int col = n0 + wc * 32 + ni * 16 + lrow;
                if constexpr (OUTMODE == 0)
                    Cb[(size_t)row * N + col] = f2bf(acc[mi][ni][r]);
                else
                    Cf[(size_t)row * N + col] = acc[mi][ni][r] + bias[col];
            }
}

// ---------------- causal Toeplitz conv, barrier-free ----------------
// out[b,i,h,:] = sum_{j<=i} z[b,h,i-j] * v[b,j,h,:]
// A[row][k] = zrev[2047-row+k]: fragments read directly from dual-parity LDS
// copies of zrev; B fragments from v^T in global (L2-resident via XCD swizzle).
// 2048 wave-tasks: (bh, slice-pair (s,63-s) of 32 rows, col-half); 65 K32-steps
// each (uniform). 512 blocks -> 2 waves/SIMD. Depth-2 B prefetch (static names).
__global__ __launch_bounds__(256) void conv_kernel(const u16* __restrict__ zr,
                                                   const u16* __restrict__ vt2,
                                                   u16* __restrict__ cv) {
    const int i = blockIdx.x;
    const int bh = (i & 7) * 4 + ((i >> 3) & 3);
    const int rest = i >> 5;                   // 0..15
    const int b = bh >> 4, h = bh & 15;
    __shared__ uint zsl[2176];  // [0..1087]=zrev dwords, [1088..]=shift-by-1-elem
    const int t = threadIdx.x;
    {
        const uint* zp = reinterpret_cast<const uint*>(zr + (size_t)bh * ZP);
        for (int q = t; q < 1088; q += 256) {
            uint v0 = (q < 1056) ? zp[q] : 0u;
            uint v1 = (q < 1055) ? zp[q + 1] : 0u;
            zsl[q] = v0;
            zsl[1088 + q] = (v0 >> 16) | (v1 << 16);
        }
    }
    __syncthreads();

    const int w = t >> 6, l = t & 63;
    const int task = rest * 4 + w;             // 0..63
    const int pp = task >> 1;                  // 0..31
    const int ch = task & 1;
    const int lrow = l & 15;
    const int lk8 = (l >> 4) * 8;
    const int col0 = ch * 32;
    const int ebase = h * 64 + col0;
    const size_t boff = (size_t)b * SEQ;

    union U { uint d[4]; short8 s8; };

    int slices[2] = {pp, 63 - pp};
#pragma unroll 1
    for (int si = 0; si < 2; si++) {
        const int s = slices[si];
        const int row0 = s * 32;
        const int nk = s + 1;                  // K32 steps
        f32x4 acc[2][2];
#pragma unroll
        for (int a = 0; a < 2; a++)
#pragma unroll
            for (int c = 0; c < 2; c++) acc[a][c] = (f32x4){0.f, 0.f, 0.f, 0.f};

        const int obase = 2047 - row0 - lrow + lk8;

        auto loadB = [&](int k0, U* bf) {
#pragma unroll
            for (int ni = 0; ni < 2; ni++) {
                const u16* p = vt2 + (((size_t)(ebase + ni * 16 + lrow)) << 12) + boff + k0 + lk8;
                *reinterpret_cast<uint4*>(bf[ni].d) = *reinterpret_cast<const uint4*>(p);
            }
        };
        auto loadA = [&](int k0, U* af) {
#pragma unroll
            for (int mi = 0; mi < 2; mi++) {
                int o = obase - mi * 16 + k0;
                uint adw = (uint)(o >> 1) + (uint)((o & 1) * 1088);
#pragma unroll
                for (int q = 0; q < 4; q++) af[mi].d[q] = zsl[adw + q];
            }
        };

        U a0[2], a1[2], b0[2], b1[2];
        loadB(0, b0);
        loadB(32, b1);          // harmless over-read if nk==1 (in-bounds)
        loadA(0, a0);
        int k = 0;
        for (; k + 1 < nk; k += 2) {
            loadA((k + 1) * 32, a1);
#pragma unroll
            for (int mi = 0; mi < 2; mi++)
#pragma unroll
                for (int ni = 0; ni < 2; ni++)
                    acc[mi][ni] = __builtin_amdgcn_mfma_f32_16x16x32_bf16(a0[mi].s8, b0[ni].s8, acc[mi][ni], 0, 0, 0);
            if (k + 2 < nk) loadB((k + 2) * 32, b0);
            loadA((k + 2) * 32, a0);   // over-read stays inside zsl (pad analyzed)
#pragma unroll
            for (int mi = 0; mi < 2; mi++)
#pragma unroll
                for (int ni = 0; ni < 2; ni++)
                    acc[mi][ni] = __builtin_amdgcn_mfma_f32_16x16x32_bf16(a1[mi].s8, b1[ni].s8, acc[mi][ni], 0, 0, 0);
            if (k + 3 < nk) loadB((k + 3) * 32, b1);
        }
        if (nk & 1) {
#pragma unroll
            for (int mi = 0; mi < 2; mi++)
#pragma unroll
                for (int ni = 0; ni < 2; ni++)
                    acc[mi][ni] = __builtin_amdgcn_mfma_f32_16x16x32_bf16(a0[mi].s8, b0[ni].s8, acc[mi][ni], 0, 0, 0);
        }
#pragma unroll
        for (int mi = 0; mi < 2; mi++)
#pragma unroll
            for (int ni = 0; ni < 2; ni++)
#pragma unroll
                for (int r = 0; r < 4; r++) {
                    int row = row0 + mi * 16 + (l >> 4) * 4 + r;
                    int col = col0 + ni * 16 + lrow;
                    cv[((size_t)b * SEQ + row) * EMB + h * 64 + col] = f2bf(acc[mi][ni][r]);
                }
    }
}

extern "C" void kernel_launch(void* const* d_in, const int* in_sizes, int n_in,
                              void* d_out, int out_size, void* d_ws, size_t ws_size,
                              hipStream_t stream) {
    const float* x   = (const float*)d_in[0];
    const float* W_A = (const float*)d_in[1];
    const float* W_V = (const float*)d_in[2];
    const float* W_O = (const float*)d_in[3];
    const float* b_O = (const float*)d_in[4];

    char* ws = (char*)d_ws;
    u16*   xb  = (u16*)(ws + 0);          // 8 MB   x bf16 [4096][1024]
    u16*   wvb = (u16*)(ws + 8388608);    // 2 MB   W_V bf16 [1024][1024]
    u16*   wob = (u16*)(ws + 10485760);   // 2 MB   W_O bf16
    float* zl  = (float*)(ws + 12582912); // 256 KB logits fp32 [B][H][S]
    u16*   zr  = (u16*)(ws + 12845056);   // 132 KB reversed softmax bf16 [B][H][ZP]
    u16*   vt2 = (u16*)(ws + 12980224);   // 8 MB   v^T bf16 [1024][B*S]
    u16*   cv  = (u16*)(ws + 21368832);   // 8 MB   conv out bf16 [4096][1024]

    cast_all<<<6144, 256, 0, stream>>>(x, W_V, W_O, xb, wvb, wob);
    logits_kernel<<<256, 256, 0, stream>>>(x, W_A, zl);
    // v^T[e][b*S+s] = sum_k W_V[e,k] * x[b,s,k]; blocks 512..543 do softmax
    gemm64<0, 0, true><<<544, 256, 0, stream>>>(wvb, xb, vt2, nullptr, nullptr,
                                                1024, 4096, 1024, zl, zr);
    conv_kernel<<<512, 256, 0, stream>>>(zr, vt2, cv);
    gemm64<1, 1, false><<<512, 256, 0, stream>>>(cv, wob, nullptr, (float*)d_out, b_O,
                                                 4096, 1024, 1024, nullptr, nullptr);
}